// Round 24
// baseline (118.151 us; speedup 1.0000x reference)
//
#include <hip/hip_runtime.h>
#include <hip/hip_fp16.h>
#include <stdint.h>

// Problem constants (hardcoded per reference)
#define NROWS 131072   // B*L
#define DIM   256      // D
#define HDK   128      // H*DK
#define BM    16       // rows per tile
#define TPB   16       // tiles per block
#define NBLK  (NROWS / BM / TPB)   // 512 blocks = 2 per CU (16 waves/CU)

typedef _Float16 f16x8 __attribute__((ext_vector_type(8)));
typedef _Float16 f16x2 __attribute__((ext_vector_type(2)));
typedef float    f32x4 __attribute__((ext_vector_type(4)));
typedef float    f32x2 __attribute__((ext_vector_type(2)));   // for nontemporal store

// LDS-ordering barrier WITHOUT the __syncthreads vmcnt(0) drain.
#define LDS_BARRIER() asm volatile("s_waitcnt lgkmcnt(0)\ns_barrier" ::: "memory")

// Opaque 16B load: volatile asm cannot be rematerialized -> the result MUST
// stay resident in VGPRs for all later uses (the R5-R18 weight-reload defeat).
__device__ __forceinline__ f16x8 ldg_opaque(const _Float16* p) {
  f16x8 r;
  asm volatile("global_load_dwordx4 %0, %1, off" : "=v"(r) : "v"(p));
  return r;
}

// ---------------------------------------------------------------------------
// Pack W_q, W_k, W_v (256x128) and W_o (128x256) into fragment-linear fp16.
// Proj p at p*32768: frag idx = ((nt*8 + ks)*64 + lane)*8 + j,
//   value = W[ks*32 + (lane>>4)*8 + j][nt*16 + (lane&15)]   (nt = head)
// W_o at 98304: frag idx = ((nto*4 + ks)*64 + lane)*8 + j, COLUMN PERMUTE:
//   actual col n = (nto>>1)*32 + (lane&15)*2 + (nto&1)
// ---------------------------------------------------------------------------
__global__ void pack_w(const float* __restrict__ Wq, const float* __restrict__ Wk,
                       const float* __restrict__ Wv, const float* __restrict__ Wo,
                       _Float16* __restrict__ wt) {
  int t = blockIdx.x * 256 + threadIdx.x;   // 0 .. 131071
  int seg = t >> 15;                        // 0..3
  int i = t & 32767;
  int j = i & 7;
  int l = (i >> 3) & 63;
  int rest = i >> 9;                        // nt*KS + ks
  const float* W;
  int N, k, n;
  if (seg < 3) {
    W = (seg == 0) ? Wq : ((seg == 1) ? Wk : Wv);
    N = HDK;
    int ks = rest & 7, nt = rest >> 3;
    k = ks * 32 + ((l >> 4) << 3) + j;      // 0..255
    n = nt * 16 + (l & 15);                 // 0..127
  } else {
    W = Wo;
    N = DIM;
    int ks = rest & 3, nt = rest >> 2;      // nt = nto in 0..15
    k = ks * 32 + ((l >> 4) << 3) + j;      // 0..127
    n = ((nt >> 1) << 5) + ((l & 15) << 1) + (nt & 1);  // permuted column
  }
  wt[t] = (_Float16)W[k * N + n];
}

// ---------------------------------------------------------------------------
// v24 = v23 champion (opaque-held weights, NT stores, premultiplied sVQ,
// one lgkm-barrier/region, retire-one-late, setprio) + RESTORED 16-wave TLP:
//  - waves_per_eu(2,4): min=2 keeps the 256-VGPR allocator budget (weight
//    hoist preserved, VGPR_Count was 112), max=4 lets the HW co-schedule a
//    second block (112x4=448 <= 512/SIMD pool; 2x72KB LDS = 144 <= 160KB).
//  - TPB 32->16, NBLK=512 = 2 blocks/CU.  Combines R19's weight pinning
//    with the 16-wave latency hiding the champion gave up.
// ---------------------------------------------------------------------------
__global__ __launch_bounds__(512)
__attribute__((amdgpu_waves_per_eu(2, 4)))
void uan_main(const float* __restrict__ Qg, const float* __restrict__ Kg,
              const float* __restrict__ Vg, const _Float16* __restrict__ wt,
              const float* __restrict__ Wl, const float* __restrict__ blv,
              const float* __restrict__ Wsv, const float* __restrict__ bsv,
              float* __restrict__ outg) {
  __shared__ __align__(16) _Float16 sF0[1536 * 8];   // 24576 B
  __shared__ __align__(16) _Float16 sF1[1536 * 8];   // 24576 B
  __shared__ __align__(16) _Float16 sVA0[256 * 8];   //  4096 B
  __shared__ __align__(16) _Float16 sVA1[256 * 8];   //  4096 B
  __shared__ __align__(16) _Float16 sVQ0[4096];      //  8192 B (2048 dwords)
  __shared__ __align__(16) _Float16 sVQ1[4096];      //  8192 B

  const int tid  = threadIdx.x;
  const int lane = tid & 63;
  const int w    = tid >> 6;        // wave 0..7 == head
  const int c16  = lane & 15;
  const int kg   = lane >> 4;

  // ---- held B-fragments: OPAQUE loads, issued back-to-back (in flight
  //      together), certified once below ----
  f16x8 bwp[24];   // proj: [p*8 + ks], head w
#pragma unroll
  for (int p = 0; p < 3; ++p)
#pragma unroll
    for (int ks = 0; ks < 8; ++ks)
      bwp[p * 8 + ks] = ldg_opaque(wt + p * 32768 +
                         (size_t)(((w * 8 + ks) * 64) + lane) * 8);
  f16x8 bo[8];     // W_o: [nt*4 + ks], tiles nto = 2w, 2w+1
#pragma unroll
  for (int nt = 0; nt < 2; ++nt)
#pragma unroll
    for (int ks = 0; ks < 4; ++ks)
      bo[nt * 4 + ks] = ldg_opaque(wt + 98304 +
                         (size_t)((((2 * w + nt) * 4 + ks) * 64) + lane) * 8);

  const float bl0 = blv[0], bl1 = blv[1], bs0 = bsv[0];
  // per-register softmax constants: hd = kg*4 + q
  float wl0q[4], wl1q[4], wsq[4];
#pragma unroll
  for (int q = 0; q < 4; ++q) {
    wl0q[q] = Wl[kg * 4 + q];
    wl1q[q] = Wl[16 + kg * 4 + q];
    wsq[q]  = Wsv[kg * 4 + q];
  }

  // staging: thread stages row (row0+c16)'s cols [w*32+kg*8, +8) of each plane
  const size_t soff  = (size_t)c16 * DIM + w * 32 + kg * 8;
  const size_t sfrag = (size_t)(w * 64 + lane) * 8;   // + p*4096 per plane

  float4 sa[3][2];
  auto issue_stage = [&](int t) {
    const size_t row0 = ((size_t)blockIdx.x * TPB + t) * BM;
#pragma unroll
    for (int p = 0; p < 3; ++p) {
      const float* base = (p == 0) ? Qg : ((p == 1) ? Kg : Vg);
      const float* src  = base + row0 * DIM + soff;
      sa[p][0] = *(const float4*)src;
      sa[p][1] = *(const float4*)(src + 4);
    }
  };
  auto write_stage = [&](_Float16* sFn, _Float16* sVQn) {
#pragma unroll
    for (int p = 0; p < 3; ++p) {
      f16x8 h;
      h[0] = (_Float16)sa[p][0].x; h[1] = (_Float16)sa[p][0].y;
      h[2] = (_Float16)sa[p][0].z; h[3] = (_Float16)sa[p][0].w;
      h[4] = (_Float16)sa[p][1].x; h[5] = (_Float16)sa[p][1].y;
      h[6] = (_Float16)sa[p][1].z; h[7] = (_Float16)sa[p][1].w;
      *(f16x8*)(sFn + p * 4096 + sfrag) = h;
    }
    // premultiplied vq = Q*V (f32 mul, single fp16 rounding), swizzled layout
    const float qf[8] = {sa[0][0].x, sa[0][0].y, sa[0][0].z, sa[0][0].w,
                         sa[0][1].x, sa[0][1].y, sa[0][1].z, sa[0][1].w};
    const float vf[8] = {sa[2][0].x, sa[2][0].y, sa[2][0].z, sa[2][0].w,
                         sa[2][1].x, sa[2][1].y, sa[2][1].z, sa[2][1].w};
#pragma unroll
    for (int i = 0; i < 4; ++i) {
      const int cp = w * 16 + kg * 4 + i;              // column-pair index
      const int a  = cp * 16 + ((c16 + cp) & 15);      // dword index (row=c16)
      f16x2 h2;
      h2[0] = (_Float16)(qf[2 * i]     * vf[2 * i]);
      h2[1] = (_Float16)(qf[2 * i + 1] * vf[2 * i + 1]);
      *(f16x2*)(sVQn + (size_t)a * 2) = h2;
    }
  };

  // retire phase: W_o MFMA from sVA + SiLU finale with carried vq pairs
  auto wo_finale = [&](const _Float16* sVp, const uint32_t* vq, int tt) {
    f32x4 accO[2] = {};
    __builtin_amdgcn_s_setprio(1);
#pragma unroll
    for (int ks = 0; ks < 4; ++ks) {
      const f16x8 af = *(const f16x8*)(sVp + (size_t)(ks * 64 + lane) * 8);
      accO[0] = __builtin_amdgcn_mfma_f32_16x16x32_f16(af, bo[ks],     accO[0], 0, 0, 0);
      accO[1] = __builtin_amdgcn_mfma_f32_16x16x32_f16(af, bo[4 + ks], accO[1], 0, 0, 0);
    }
    __builtin_amdgcn_s_setprio(0);
    const size_t row0 = ((size_t)blockIdx.x * TPB + tt) * BM;
#pragma unroll
    for (int q = 0; q < 4; ++q) {
      const f16x2 h2 = __builtin_bit_cast(f16x2, vq[q]);
      const float att0 = (float)h2[0] * accO[0][q];
      const float att1 = (float)h2[1] * accO[1][q];
      f32x2 o;
      o[0] = att0 / (1.f + __expf(-att0));
      o[1] = att1 / (1.f + __expf(-att1));
      const size_t gb = (row0 + kg * 4 + q) * DIM + w * 32 + c16 * 2;
      __builtin_nontemporal_store(o, (f32x2*)(outg + gb));   // no cache alloc
    }
  };

  // carried finale operands (read region t, consumed region t+1)
  uint32_t cvq[4];

  // prologue: stage tile 0; certify ALL outstanding loads (weights + stage)
  issue_stage(0);
  asm volatile("s_waitcnt vmcnt(0)" ::: "memory");
  __builtin_amdgcn_sched_barrier(0);   // rule #18: pin consumers after wait
  write_stage(sF0, sVQ0);
  LDS_BARRIER();

  for (int t = 0; t < TPB; ++t) {
    _Float16* sFc  = (t & 1) ? sF1 : sF0;
    _Float16* sFn  = (t & 1) ? sF0 : sF1;
    _Float16* sVc  = (t & 1) ? sVA1 : sVA0;
    _Float16* sVp  = (t & 1) ? sVA0 : sVA1;
    _Float16* sVQc = (t & 1) ? sVQ1 : sVQ0;
    _Float16* sVQn = (t & 1) ? sVQ0 : sVQ1;
    const bool more = (t + 1 < TPB);
    if (more) issue_stage(t + 1);        // next-tile global loads in flight

    // ---- projections, swapped operands: accP holds P^T (row=c16, hd=kg*4+q) ----
    f32x4 accP[3] = {};
    __builtin_amdgcn_s_setprio(1);
#pragma unroll
    for (int p = 0; p < 3; ++p)
#pragma unroll
      for (int ks = 0; ks < 8; ++ks) {
        const f16x8 af = *(const f16x8*)(sFc + (size_t)(((p * 8 + ks) * 64) + lane) * 8);
        accP[p] = __builtin_amdgcn_mfma_f32_16x16x32_f16(bwp[p * 8 + ks], af, accP[p], 0, 0, 0);
      }
    __builtin_amdgcn_s_setprio(0);

    // ---- gated softmax: head-dim is register axis; reduce = 3 adds + 2 shfl ----
    float va[4];
    {
      float left[4], right[4];
      float pd0 = 0.f, pd1 = 0.f;
#pragma unroll
      for (int q = 0; q < 4; ++q) {
        const float qh = accP[0][q], kh = accP[1][q], vh = accP[2][q];
        left[q]  = kh * qh;
        right[q] = vh * qh;
        pd0 += left[q] * wl0q[q];
        pd1 += left[q] * wl1q[q];
      }
      pd0 += __shfl_xor(pd0, 16); pd0 += __shfl_xor(pd0, 32);
      pd1 += __shfl_xor(pd1, 16); pd1 += __shfl_xor(pd1, 32);
      const float m0 = 1.f / (1.f + __expf(-(pd0 + bl0)));
      const float m1 = 1.f / (1.f + __expf(-(pd1 + bl1)));
      const float mm = m0 * m1;
      float pnum = 0.f, pden = 0.f;
      float ev[4];
#pragma unroll
      for (int q = 0; q < 4; ++q) {
        ev[q] = __expf(left[q] * mm);    // |arg| <~ 40: f32-safe without max-sub
        pnum += ev[q] * wsq[q];
        pden += ev[q];
      }
      pnum += __shfl_xor(pnum, 16); pnum += __shfl_xor(pnum, 32);
      pden += __shfl_xor(pden, 16); pden += __shfl_xor(pden, 32);
      const float score = pnum / pden + bs0;
#pragma unroll
      for (int q = 0; q < 4; ++q) va[q] = score * right[q];
    }

    // ---- store V_att^T values into W_o A-fragment layout (double-buffered) ----
#pragma unroll
    for (int q = 0; q < 4; ++q) {
      const int k = w * 16 + kg * 4 + q;
      sVc[(size_t)((k >> 5) * 64 + ((k >> 3) & 3) * 16 + c16) * 8 + (k & 7)]
          = (_Float16)va[q];
    }

    // ---- read this tile's vq pairs (bank-clean swizzled table) ----
    uint32_t nvq[4];
    {
      const int cp = w * 16 + c16;
#pragma unroll
      for (int q = 0; q < 4; ++q) {
        const int a = cp * 16 + ((kg * 4 + q + cp) & 15);
        nvq[q] = *(const uint32_t*)(sVQc + (size_t)a * 2);
      }
    }

    // ---- retire previous tile: W_o(t-1) + finale(t-1) (independent work) ----
    if (t > 0) wo_finale(sVp, cvq, t - 1);
#pragma unroll
    for (int q = 0; q < 4; ++q) cvq[q] = nvq[q];

    // ---- next-tile staging write (vmcnt drain at region END, max cover) ----
    if (more) write_stage(sFn, sVQn);

    LDS_BARRIER();   // the ONLY barrier per region
  }

  // epilogue: retire the last tile
  wo_finale((TPB & 1) ? sVA0 : sVA1, cvq, TPB - 1);
}

// ---------------------------------------------------------------------------
extern "C" void kernel_launch(void* const* d_in, const int* in_sizes, int n_in,
                              void* d_out, int out_size, void* d_ws, size_t ws_size,
                              hipStream_t stream) {
  const float* Q  = (const float*)d_in[0];
  const float* K  = (const float*)d_in[1];
  const float* V  = (const float*)d_in[2];
  const float* Wq = (const float*)d_in[3];
  const float* Wk = (const float*)d_in[4];
  const float* Wv = (const float*)d_in[5];
  const float* Wo = (const float*)d_in[6];
  const float* Wl = (const float*)d_in[7];
  const float* bl = (const float*)d_in[8];
  const float* Ws = (const float*)d_in[9];
  const float* bs = (const float*)d_in[10];
  _Float16* wt = (_Float16*)d_ws;   // 131072 halves = 256 KB of scratch
  float* out = (float*)d_out;

  pack_w<<<512, 256, 0, stream>>>(Wq, Wk, Wv, Wo, wt);
  uan_main<<<NBLK, 512, 0, stream>>>(Q, K, V, wt, Wl, bl, Ws, bs, out);
}

// Round 25
// 114.934 us; speedup vs baseline: 1.0280x; 1.0280x over previous
//
#include <hip/hip_runtime.h>
#include <hip/hip_fp16.h>
#include <stdint.h>

// Problem constants (hardcoded per reference)
#define NROWS 131072   // B*L
#define DIM   256      // D
#define HDK   128      // H*DK
#define BM    16       // rows per tile
#define TPB   32       // tiles per block
#define NBLK  (NROWS / BM / TPB)   // 256 blocks = 1 per CU, no rounds

typedef _Float16 f16x8 __attribute__((ext_vector_type(8)));
typedef _Float16 f16x2 __attribute__((ext_vector_type(2)));
typedef float    f32x4 __attribute__((ext_vector_type(4)));
typedef float    f32x2 __attribute__((ext_vector_type(2)));   // for nontemporal store

// LDS-ordering barrier WITHOUT the __syncthreads vmcnt(0) drain.
#define LDS_BARRIER() asm volatile("s_waitcnt lgkmcnt(0)\ns_barrier" ::: "memory")

// Opaque 16B load: volatile asm cannot be rematerialized -> the result MUST
// stay resident in VGPRs for all later uses (the R5-R18 weight-reload defeat).
__device__ __forceinline__ f16x8 ldg_opaque(const _Float16* p) {
  f16x8 r;
  asm volatile("global_load_dwordx4 %0, %1, off" : "=v"(r) : "v"(p));
  return r;
}

// ---------------------------------------------------------------------------
// Pack W_q, W_k, W_v (256x128) and W_o (128x256) into fragment-linear fp16.
// Proj p at p*32768: frag idx = ((nt*8 + ks)*64 + lane)*8 + j,
//   value = W[ks*32 + (lane>>4)*8 + j][nt*16 + (lane&15)]   (nt = head)
// W_o at 98304: frag idx = ((nto*4 + ks)*64 + lane)*8 + j, COLUMN PERMUTE:
//   actual col n = (nto>>1)*32 + (lane&15)*2 + (nto&1)
// ---------------------------------------------------------------------------
__global__ void pack_w(const float* __restrict__ Wq, const float* __restrict__ Wk,
                       const float* __restrict__ Wv, const float* __restrict__ Wo,
                       _Float16* __restrict__ wt) {
  int t = blockIdx.x * 256 + threadIdx.x;   // 0 .. 131071
  int seg = t >> 15;                        // 0..3
  int i = t & 32767;
  int j = i & 7;
  int l = (i >> 3) & 63;
  int rest = i >> 9;                        // nt*KS + ks
  const float* W;
  int N, k, n;
  if (seg < 3) {
    W = (seg == 0) ? Wq : ((seg == 1) ? Wk : Wv);
    N = HDK;
    int ks = rest & 7, nt = rest >> 3;
    k = ks * 32 + ((l >> 4) << 3) + j;      // 0..255
    n = nt * 16 + (l & 15);                 // 0..127
  } else {
    W = Wo;
    N = DIM;
    int ks = rest & 3, nt = rest >> 2;      // nt = nto in 0..15
    k = ks * 32 + ((l >> 4) << 3) + j;      // 0..127
    n = ((nt >> 1) << 5) + ((l & 15) << 1) + (nt & 1);  // permuted column
  }
  wt[t] = (_Float16)W[k * N + n];
}

// ---------------------------------------------------------------------------
// v25 = v23 champion, verbatim (final state).  24-round ledger:
//   fp16-MFMA restructure 245 -> register-axis softmax + pipelined staging
//   147 -> finale-from-LDS 135 -> cross-barrier retire 131 -> opaque-pinned
//   weights 118.4 -> NT stores 115.6 µs.
// Structure: register-staged depth-1 pipeline, one lgkm-barrier/region,
// retire-one-late W_o, premultiplied bank-clean sVQ, setprio on MFMA,
// weights held via opaque asm loads, waves_per_eu(2,2) 256-VGPR budget,
// 1 block/CU, non-temporal output stores.
// ---------------------------------------------------------------------------
__global__ __launch_bounds__(512)
__attribute__((amdgpu_waves_per_eu(2, 2)))
void uan_main(const float* __restrict__ Qg, const float* __restrict__ Kg,
              const float* __restrict__ Vg, const _Float16* __restrict__ wt,
              const float* __restrict__ Wl, const float* __restrict__ blv,
              const float* __restrict__ Wsv, const float* __restrict__ bsv,
              float* __restrict__ outg) {
  __shared__ __align__(16) _Float16 sF0[1536 * 8];   // 24576 B
  __shared__ __align__(16) _Float16 sF1[1536 * 8];   // 24576 B
  __shared__ __align__(16) _Float16 sVA0[256 * 8];   //  4096 B
  __shared__ __align__(16) _Float16 sVA1[256 * 8];   //  4096 B
  __shared__ __align__(16) _Float16 sVQ0[4096];      //  8192 B (2048 dwords)
  __shared__ __align__(16) _Float16 sVQ1[4096];      //  8192 B

  const int tid  = threadIdx.x;
  const int lane = tid & 63;
  const int w    = tid >> 6;        // wave 0..7 == head
  const int c16  = lane & 15;
  const int kg   = lane >> 4;

  // ---- held B-fragments: OPAQUE loads, issued back-to-back (in flight
  //      together), certified once below ----
  f16x8 bwp[24];   // proj: [p*8 + ks], head w
#pragma unroll
  for (int p = 0; p < 3; ++p)
#pragma unroll
    for (int ks = 0; ks < 8; ++ks)
      bwp[p * 8 + ks] = ldg_opaque(wt + p * 32768 +
                         (size_t)(((w * 8 + ks) * 64) + lane) * 8);
  f16x8 bo[8];     // W_o: [nt*4 + ks], tiles nto = 2w, 2w+1
#pragma unroll
  for (int nt = 0; nt < 2; ++nt)
#pragma unroll
    for (int ks = 0; ks < 4; ++ks)
      bo[nt * 4 + ks] = ldg_opaque(wt + 98304 +
                         (size_t)((((2 * w + nt) * 4 + ks) * 64) + lane) * 8);

  const float bl0 = blv[0], bl1 = blv[1], bs0 = bsv[0];
  // per-register softmax constants: hd = kg*4 + q
  float wl0q[4], wl1q[4], wsq[4];
#pragma unroll
  for (int q = 0; q < 4; ++q) {
    wl0q[q] = Wl[kg * 4 + q];
    wl1q[q] = Wl[16 + kg * 4 + q];
    wsq[q]  = Wsv[kg * 4 + q];
  }

  // staging: thread stages row (row0+c16)'s cols [w*32+kg*8, +8) of each plane
  const size_t soff  = (size_t)c16 * DIM + w * 32 + kg * 8;
  const size_t sfrag = (size_t)(w * 64 + lane) * 8;   // + p*4096 per plane

  float4 sa[3][2];
  auto issue_stage = [&](int t) {
    const size_t row0 = ((size_t)blockIdx.x * TPB + t) * BM;
#pragma unroll
    for (int p = 0; p < 3; ++p) {
      const float* base = (p == 0) ? Qg : ((p == 1) ? Kg : Vg);
      const float* src  = base + row0 * DIM + soff;
      sa[p][0] = *(const float4*)src;
      sa[p][1] = *(const float4*)(src + 4);
    }
  };
  auto write_stage = [&](_Float16* sFn, _Float16* sVQn) {
#pragma unroll
    for (int p = 0; p < 3; ++p) {
      f16x8 h;
      h[0] = (_Float16)sa[p][0].x; h[1] = (_Float16)sa[p][0].y;
      h[2] = (_Float16)sa[p][0].z; h[3] = (_Float16)sa[p][0].w;
      h[4] = (_Float16)sa[p][1].x; h[5] = (_Float16)sa[p][1].y;
      h[6] = (_Float16)sa[p][1].z; h[7] = (_Float16)sa[p][1].w;
      *(f16x8*)(sFn + p * 4096 + sfrag) = h;
    }
    // premultiplied vq = Q*V (f32 mul, single fp16 rounding), swizzled layout
    const float qf[8] = {sa[0][0].x, sa[0][0].y, sa[0][0].z, sa[0][0].w,
                         sa[0][1].x, sa[0][1].y, sa[0][1].z, sa[0][1].w};
    const float vf[8] = {sa[2][0].x, sa[2][0].y, sa[2][0].z, sa[2][0].w,
                         sa[2][1].x, sa[2][1].y, sa[2][1].z, sa[2][1].w};
#pragma unroll
    for (int i = 0; i < 4; ++i) {
      const int cp = w * 16 + kg * 4 + i;              // column-pair index
      const int a  = cp * 16 + ((c16 + cp) & 15);      // dword index (row=c16)
      f16x2 h2;
      h2[0] = (_Float16)(qf[2 * i]     * vf[2 * i]);
      h2[1] = (_Float16)(qf[2 * i + 1] * vf[2 * i + 1]);
      *(f16x2*)(sVQn + (size_t)a * 2) = h2;
    }
  };

  // retire phase: W_o MFMA from sVA + SiLU finale with carried vq pairs
  auto wo_finale = [&](const _Float16* sVp, const uint32_t* vq, int tt) {
    f32x4 accO[2] = {};
    __builtin_amdgcn_s_setprio(1);
#pragma unroll
    for (int ks = 0; ks < 4; ++ks) {
      const f16x8 af = *(const f16x8*)(sVp + (size_t)(ks * 64 + lane) * 8);
      accO[0] = __builtin_amdgcn_mfma_f32_16x16x32_f16(af, bo[ks],     accO[0], 0, 0, 0);
      accO[1] = __builtin_amdgcn_mfma_f32_16x16x32_f16(af, bo[4 + ks], accO[1], 0, 0, 0);
    }
    __builtin_amdgcn_s_setprio(0);
    const size_t row0 = ((size_t)blockIdx.x * TPB + tt) * BM;
#pragma unroll
    for (int q = 0; q < 4; ++q) {
      const f16x2 h2 = __builtin_bit_cast(f16x2, vq[q]);
      const float att0 = (float)h2[0] * accO[0][q];
      const float att1 = (float)h2[1] * accO[1][q];
      f32x2 o;
      o[0] = att0 / (1.f + __expf(-att0));
      o[1] = att1 / (1.f + __expf(-att1));
      const size_t gb = (row0 + kg * 4 + q) * DIM + w * 32 + c16 * 2;
      __builtin_nontemporal_store(o, (f32x2*)(outg + gb));   // no cache alloc
    }
  };

  // carried finale operands (read region t, consumed region t+1)
  uint32_t cvq[4];

  // prologue: stage tile 0; certify ALL outstanding loads (weights + stage)
  issue_stage(0);
  asm volatile("s_waitcnt vmcnt(0)" ::: "memory");
  __builtin_amdgcn_sched_barrier(0);   // rule #18: pin consumers after wait
  write_stage(sF0, sVQ0);
  LDS_BARRIER();

  for (int t = 0; t < TPB; ++t) {
    _Float16* sFc  = (t & 1) ? sF1 : sF0;
    _Float16* sFn  = (t & 1) ? sF0 : sF1;
    _Float16* sVc  = (t & 1) ? sVA1 : sVA0;
    _Float16* sVp  = (t & 1) ? sVA0 : sVA1;
    _Float16* sVQc = (t & 1) ? sVQ1 : sVQ0;
    _Float16* sVQn = (t & 1) ? sVQ0 : sVQ1;
    const bool more = (t + 1 < TPB);
    if (more) issue_stage(t + 1);        // next-tile global loads in flight

    // ---- projections, swapped operands: accP holds P^T (row=c16, hd=kg*4+q) ----
    f32x4 accP[3] = {};
    __builtin_amdgcn_s_setprio(1);
#pragma unroll
    for (int p = 0; p < 3; ++p)
#pragma unroll
      for (int ks = 0; ks < 8; ++ks) {
        const f16x8 af = *(const f16x8*)(sFc + (size_t)(((p * 8 + ks) * 64) + lane) * 8);
        accP[p] = __builtin_amdgcn_mfma_f32_16x16x32_f16(bwp[p * 8 + ks], af, accP[p], 0, 0, 0);
      }
    __builtin_amdgcn_s_setprio(0);

    // ---- gated softmax: head-dim is register axis; reduce = 3 adds + 2 shfl ----
    float va[4];
    {
      float left[4], right[4];
      float pd0 = 0.f, pd1 = 0.f;
#pragma unroll
      for (int q = 0; q < 4; ++q) {
        const float qh = accP[0][q], kh = accP[1][q], vh = accP[2][q];
        left[q]  = kh * qh;
        right[q] = vh * qh;
        pd0 += left[q] * wl0q[q];
        pd1 += left[q] * wl1q[q];
      }
      pd0 += __shfl_xor(pd0, 16); pd0 += __shfl_xor(pd0, 32);
      pd1 += __shfl_xor(pd1, 16); pd1 += __shfl_xor(pd1, 32);
      const float m0 = 1.f / (1.f + __expf(-(pd0 + bl0)));
      const float m1 = 1.f / (1.f + __expf(-(pd1 + bl1)));
      const float mm = m0 * m1;
      float pnum = 0.f, pden = 0.f;
      float ev[4];
#pragma unroll
      for (int q = 0; q < 4; ++q) {
        ev[q] = __expf(left[q] * mm);    // |arg| <~ 40: f32-safe without max-sub
        pnum += ev[q] * wsq[q];
        pden += ev[q];
      }
      pnum += __shfl_xor(pnum, 16); pnum += __shfl_xor(pnum, 32);
      pden += __shfl_xor(pden, 16); pden += __shfl_xor(pden, 32);
      const float score = pnum / pden + bs0;
#pragma unroll
      for (int q = 0; q < 4; ++q) va[q] = score * right[q];
    }

    // ---- store V_att^T values into W_o A-fragment layout (double-buffered) ----
#pragma unroll
    for (int q = 0; q < 4; ++q) {
      const int k = w * 16 + kg * 4 + q;
      sVc[(size_t)((k >> 5) * 64 + ((k >> 3) & 3) * 16 + c16) * 8 + (k & 7)]
          = (_Float16)va[q];
    }

    // ---- read this tile's vq pairs (bank-clean swizzled table) ----
    uint32_t nvq[4];
    {
      const int cp = w * 16 + c16;
#pragma unroll
      for (int q = 0; q < 4; ++q) {
        const int a = cp * 16 + ((kg * 4 + q + cp) & 15);
        nvq[q] = *(const uint32_t*)(sVQc + (size_t)a * 2);
      }
    }

    // ---- retire previous tile: W_o(t-1) + finale(t-1) (independent work) ----
    if (t > 0) wo_finale(sVp, cvq, t - 1);
#pragma unroll
    for (int q = 0; q < 4; ++q) cvq[q] = nvq[q];

    // ---- next-tile staging write (vmcnt drain at region END, max cover) ----
    if (more) write_stage(sFn, sVQn);

    LDS_BARRIER();   // the ONLY barrier per region
  }

  // epilogue: retire the last tile
  wo_finale((TPB & 1) ? sVA0 : sVA1, cvq, TPB - 1);
}

// ---------------------------------------------------------------------------
extern "C" void kernel_launch(void* const* d_in, const int* in_sizes, int n_in,
                              void* d_out, int out_size, void* d_ws, size_t ws_size,
                              hipStream_t stream) {
  const float* Q  = (const float*)d_in[0];
  const float* K  = (const float*)d_in[1];
  const float* V  = (const float*)d_in[2];
  const float* Wq = (const float*)d_in[3];
  const float* Wk = (const float*)d_in[4];
  const float* Wv = (const float*)d_in[5];
  const float* Wo = (const float*)d_in[6];
  const float* Wl = (const float*)d_in[7];
  const float* bl = (const float*)d_in[8];
  const float* Ws = (const float*)d_in[9];
  const float* bs = (const float*)d_in[10];
  _Float16* wt = (_Float16*)d_ws;   // 131072 halves = 256 KB of scratch
  float* out = (float*)d_out;

  pack_w<<<512, 256, 0, stream>>>(Wq, Wk, Wv, Wo, wt);
  uan_main<<<NBLK, 512, 0, stream>>>(Q, K, V, wt, Wl, bl, Ws, bs, out);
}